// Round 1
// 721.792 us; speedup vs baseline: 1.0002x; 1.0002x over previous
//
#include <hip/hip_runtime.h>
#include <hip/hip_bf16.h>

// LIF layer: lif_input[T,NOUT] = x[T,NIN] @ W[NOUT,NIN]^T (fp32), then sequential scan.
// fp32 GEMM on matrix pipe via fp16 2-way SCALED split, 3 MFMA products:
//   a = a0 + a1*2^-12 (a1 pre-scaled by 2^12: dodges fp16 subnormal flush)
//   C = acc0(A0B0) + 2^-12 * acc1(A0B1 + A1B0); error ~2^-24|ab| (fp32-noise level).
// Round-7 change (scan only; GEMM untouched for attribution):
//  - lif_scan rewritten as LDS-ring prefetch: 16 chunks x 4 rows x 256 B ring,
//    global_load_lds (16B/lane) stages 4 rows per instruction, 16 GLLs in flight
//    = 64-row latency window (~2400+ cyc) with ZERO VGPR-array pressure.
//    Counted vmcnt (14 early / 63 steady, never 0) + 2-chunk register pipeline
//    for the ds_reads. Old pf[16] scheme measured ~285 us (342 cyc/step vs
//    ~25 cyc/step serial-VALU floor) -- latency pipeline was not functioning.

#define T_STEPS 2000
#define NIN_K   8192
#define NOUT_N  4096
#define MPAD    2048

typedef __attribute__((ext_vector_type(8))) _Float16 half8;  // 8 fp16 = 4 VGPRs
typedef __attribute__((ext_vector_type(4))) float f32x4;

#define GLL16(g, l)                                                              \
    __builtin_amdgcn_global_load_lds(                                            \
        (const __attribute__((address_space(1))) void*)(g),                      \
        (__attribute__((address_space(3))) void*)(l), 16, 0, 0)

// ---------------- decompose: fp32 -> (hi, lo*2^12) fp16 ----------------
__global__ __launch_bounds__(256) void split_f32(const float* __restrict__ src,
                                                 _Float16* __restrict__ hi,
                                                 _Float16* __restrict__ lo,
                                                 size_t n_valid) {
    const size_t i8 = (size_t)(blockIdx.x * 256u + threadIdx.x) * 8;
    float vv[8];
    if (i8 < n_valid) {
        float4 v0 = *(const float4*)(src + i8);
        float4 v1 = *(const float4*)(src + i8 + 4);
        vv[0] = v0.x; vv[1] = v0.y; vv[2] = v0.z; vv[3] = v0.w;
        vv[4] = v1.x; vv[5] = v1.y; vv[6] = v1.z; vv[7] = v1.w;
    } else {
#pragma unroll
        for (int j = 0; j < 8; ++j) vv[j] = 0.f;
    }
    half8 h8, l8;
#pragma unroll
    for (int j = 0; j < 8; ++j) {
        _Float16 h = (_Float16)vv[j];               // RN
        float r = __fsub_rn(vv[j], (float)h);       // exact
        h8[j] = h;
        l8[j] = (_Float16)(r * 4096.0f);            // exact shift + one RN
    }
    *(half8*)(hi + i8) = h8;
    *(half8*)(lo + i8) = l8;
}

// ---------------- split-fp16 MFMA GEMM, BK=64 ----------------
// Block tile 128x128, 4 waves of 64x64 (4x4 frags of 16x16x32), 128 K-iters.
// LDS row layout: [row][64 halves] = 128 B/row; 16B slot s of row r holds TRUE
// k-group s^(r&7) (stage-side per-lane global-address swizzle). Fragment for
// (kstep,quad) reads slot (kstep*4+quad)^(r&7) -> 8 distinct banks, 2-way, free.
// NOTE (round-7 analysis): per K=32 substep each wave reads 16 KB LDS for 48
// MFMAs = 341 B/MFMA; at full MFMA rate that is ~410 B/cyc/CU vs 256 B/clk LDS
// port -> MfmaUtil capped ~62%. Measured 52% with bank-conflict=0: this kernel
// is near its LDS-BW structural cap; bigger wave tile needed to go past it.
__global__ __launch_bounds__(256, 2) void gemm_f16x2(const _Float16* __restrict__ A0,
                                                     const _Float16* __restrict__ A1,
                                                     const _Float16* __restrict__ B0,
                                                     const _Float16* __restrict__ B1,
                                                     float* __restrict__ C) {
    __shared__ _Float16 lds[4][128 * 64];  // A0,A1,B0,B1: 16 KB each = 64 KB

    const int tid  = threadIdx.x;
    const int wave = tid >> 6;
    const int lane = tid & 63;
    const int bm = blockIdx.y * 128;
    const int bn = blockIdx.x * 128;
    const int wm = (wave >> 1) * 64;
    const int wn = (wave & 1) * 64;

    // Staging: per c-chunk, thread covers row c*32 + (tid>>3), 16B slot tid&7.
    // Global k-group swizzled: (tid&7) ^ ((tid>>3)&7)  [(tid>>3)&7 == row&7]
    const int srow = tid >> 3;                       // 0..31
    const int skswz = ((tid & 7) ^ (srow & 7)) * 8;  // halves

    f32x4 acc0[4][4], acc1[4][4];
#pragma unroll
    for (int i = 0; i < 4; ++i)
#pragma unroll
        for (int j = 0; j < 4; ++j) {
            acc0[i][j] = (f32x4){0.f, 0.f, 0.f, 0.f};
            acc1[i][j] = (f32x4){0.f, 0.f, 0.f, 0.f};
        }

    const int quad = lane >> 4;
    const int l16  = lane & 15;

    for (int k0 = 0; k0 < NIN_K; k0 += 64) {
        __syncthreads();  // previous compute done before overwriting LDS
#pragma unroll
        for (int c = 0; c < 4; ++c) {  // 4 chunks of 32 rows
            const size_t ga = (size_t)(bm + c * 32 + srow) * NIN_K + k0 + skswz;
            const size_t gb = (size_t)(bn + c * 32 + srow) * NIN_K + k0 + skswz;
            const int base = (c * 32 + wave * 8) * 64;  // wave-uniform (HW adds lane*16B)
            GLL16(A0 + ga, &lds[0][base]);
            GLL16(A1 + ga, &lds[1][base]);
            GLL16(B0 + gb, &lds[2][base]);
            GLL16(B1 + gb, &lds[3][base]);
        }
        __syncthreads();  // staging complete

#pragma unroll
        for (int ks = 0; ks < 2; ++ks) {  // two K=32 sub-steps
            half8 b0f[4], b1f[4];
#pragma unroll
            for (int j = 0; j < 4; ++j) {
                const int row = wn + j * 16 + l16;
                const int off = row * 64 + ((ks * 4 + quad) ^ (row & 7)) * 8;
                b0f[j] = *(const half8*)&lds[2][off];
                b1f[j] = *(const half8*)&lds[3][off];
            }
#pragma unroll
            for (int i = 0; i < 4; ++i) {
                const int row = wm + i * 16 + l16;
                const int off = row * 64 + ((ks * 4 + quad) ^ (row & 7)) * 8;
                const half8 a0f = *(const half8*)&lds[0][off];
                const half8 a1f = *(const half8*)&lds[1][off];
#pragma unroll
                for (int j = 0; j < 4; ++j) {
                    acc0[i][j] = __builtin_amdgcn_mfma_f32_16x16x32_f16(a0f, b0f[j], acc0[i][j], 0, 0, 0);
                    acc1[i][j] = __builtin_amdgcn_mfma_f32_16x16x32_f16(a0f, b1f[j], acc1[i][j], 0, 0, 0);
                    acc1[i][j] = __builtin_amdgcn_mfma_f32_16x16x32_f16(a1f, b0f[j], acc1[i][j], 0, 0, 0);
                }
            }
        }
    }

    // C/D layout (m89-verified): col = lane&15, row = quad*4 + reg
    const float s = 1.0f / 4096.0f;
#pragma unroll
    for (int i = 0; i < 4; ++i)
#pragma unroll
        for (int j = 0; j < 4; ++j) {
            const int m = bm + wm + i * 16 + quad * 4;
            const int n = bn + wn + j * 16 + l16;
            float* cp = C + (size_t)m * NOUT_N + n;
#pragma unroll
            for (int r = 0; r < 4; ++r)
                cp[(size_t)r * NOUT_N] = __fmaf_rn(acc1[i][j][r], s, acc0[i][j][r]);
        }
}

// ---------------- fallback fp32 GEMM (round-1 proven; reads RAW x/w) ----------------
#define BM 64
#define BN 64
#define BK 16
#define PAD 4
__global__ __launch_bounds__(256) void gemm_bt(const float* __restrict__ A,
                                               const float* __restrict__ B,
                                               float* __restrict__ C,
                                               int M, int N, int K) {
    __shared__ float As[BK][BM + PAD];
    __shared__ float Bs[BK][BN + PAD];
    const int bm = blockIdx.y * BM, bn = blockIdx.x * BN;
    const int tid = threadIdx.x;
    const int tx = tid & 15, ty = tid >> 4;
    const int lrow = tid >> 2, lk = (tid & 3) * 4;
    float acc[4][4];
#pragma unroll
    for (int i = 0; i < 4; ++i)
#pragma unroll
        for (int j = 0; j < 4; ++j) acc[i][j] = 0.0f;
    for (int k0 = 0; k0 < K; k0 += BK) {
        const int am = bm + lrow;
        float4 av = (am < M) ? *(const float4*)(A + (size_t)am * K + k0 + lk)
                             : make_float4(0.f, 0.f, 0.f, 0.f);
        As[lk + 0][lrow] = av.x; As[lk + 1][lrow] = av.y;
        As[lk + 2][lrow] = av.z; As[lk + 3][lrow] = av.w;
        float4 bv = *(const float4*)(B + (size_t)(bn + lrow) * K + k0 + lk);
        Bs[lk + 0][lrow] = bv.x; Bs[lk + 1][lrow] = bv.y;
        Bs[lk + 2][lrow] = bv.z; Bs[lk + 3][lrow] = bv.w;
        __syncthreads();
#pragma unroll
        for (int k = 0; k < BK; ++k) {
            float a[4], b[4];
#pragma unroll
            for (int i = 0; i < 4; ++i) a[i] = As[k][ty * 4 + i];
#pragma unroll
            for (int j = 0; j < 4; ++j) b[j] = Bs[k][tx * 4 + j];
#pragma unroll
            for (int i = 0; i < 4; ++i)
#pragma unroll
                for (int j = 0; j < 4; ++j) acc[i][j] += a[i] * b[j];
        }
        __syncthreads();
    }
#pragma unroll
    for (int i = 0; i < 4; ++i) {
        const int m = bm + ty * 4 + i;
        if (m < M) {
            float* cp = C + (size_t)m * N + bn + tx * 4;
#pragma unroll
            for (int j = 0; j < 4; ++j) cp[j] = acc[i][j];
        }
    }
}

// zero-fill pad rows of lif (fallback path only; main path writes them via GEMM)
__global__ void zero_rows(float* __restrict__ p, size_t n) {
    const size_t i = (size_t)blockIdx.x * 256 + threadIdx.x;
    if (i < n) p[i] = 0.0f;
}

// ---------------- sequential LIF scan (round 7: LDS-ring GLL prefetch) ----------------
// One wave (64 lanes) per 64 neurons. Ring = 16 chunks x 4 rows x 64 floats (16 KB).
// Chunk c = lif rows 4c..4c+3. One GLL16 stages a whole chunk:
//   lane l: global = inp[(4c + (l>>4))*N + jbase + (l&15)*4 ...16B]
//   LDS HW dest = base + l*16  ->  exactly [4][64] row-major. (verified mapping)
// 16 GLLs in flight = 64-row window. vmcnt discipline (in-order retirement,
// m135): before ds_read(chunk c+2), GLL(c+2) has 14 younger GLLs + 4*cc younger
// stores -> need N <= 14+4cc: vmcnt(14) for cc<14, vmcnt(63) steady (never 0).
// Slot-reuse race: GLL(c+16) rewrites chunk c's slot; chunk c was ds_read 2
// iters (~250cy) earlier and GLL's LDS write lands >=500cy after issue. Safe.
// Step arithmetic bit-identical to round 6 (absmax 0.0 preserved).
__global__ __launch_bounds__(64) void lif_scan(const float* __restrict__ inp,
                                               const float* __restrict__ v_th_p,
                                               const float* __restrict__ v_rest_p,
                                               const float* __restrict__ v_reset_p,
                                               const float* __restrict__ t_ref_p,
                                               const float* __restrict__ tau_p,
                                               float* __restrict__ out) {
    __shared__ float ring[16 * 256];  // 16 chunks x (4 rows x 64 floats)
    const int lane  = threadIdx.x;    // 0..63 (one wave)
    const int jbase = blockIdx.x * 64;
    const int j = jbase + lane;
    const int N = NOUT_N;

    const float vth = v_th_p[j], vrest = v_rest_p[j], vres = v_reset_p[j];
    const float tref = t_ref_p[j];
    const float cleak = __fmul_rn(0.001f, tau_p[j]);
    float v = vrest, refrac = 0.0f;
    out[j] = 0.0f;  // row 0 stays zero

    const int lrow = lane >> 4;         // 0..3   (row within chunk)
    const int lcol = (lane & 15) * 4;   // 0..60  (float col within row)

// stage chunk cx (rows 4cx..4cx+3, all <= 2047 when cx <= 511; pad rows are zeros)
#define GLLC(cx)                                                                  \
    {                                                                             \
        const float* _src = inp + (size_t)(4 * (cx) + lrow) * NOUT_N + jbase + lcol; \
        GLL16(_src, &ring[((cx) & 15) * 256]);                                    \
    }

// one LIF step, bit-identical arithmetic to round 6
#define STEP(t, in)                                                               \
    {                                                                             \
        const float dd = __fmul_rn(cleak, __fsub_rn(v, vrest));                   \
        v = __fsub_rn(v, dd);                                                     \
        v = (refrac == 0.0f) ? __fadd_rn(v, (in)) : v;                            \
        refrac = (refrac > 0.0f) ? (refrac - 0.001f) : 0.0f;                      \
        const bool s = (__fsub_rn(v, vth) >= 0.0f);                               \
        out[(size_t)(t) * N + j] = s ? 1.0f : 0.0f;                               \
        refrac = s ? tref : refrac;                                               \
        v = s ? vres : v;                                                         \
    }

// half-iteration: issue far-ahead GLL, wait for chunk cc+2, ds_read it into n*,
// compute the 4 steps of chunk cc from registers P*, then rotate n* -> P*.
#define HALF(cc, WAITSTR, P0, P1, P2, P3)                                         \
    {                                                                             \
        if ((cc) + 16 <= 511) GLLC((cc) + 16);                                    \
        asm volatile(WAITSTR ::: "memory");                                       \
        const int _slot = (((cc) + 2) & 15) * 256;                                \
        const float _n0 = ring[_slot + 0 * 64 + lane];                            \
        const float _n1 = ring[_slot + 1 * 64 + lane];                            \
        const float _n2 = ring[_slot + 2 * 64 + lane];                            \
        const float _n3 = ring[_slot + 3 * 64 + lane];                            \
        const int _tb = 4 * (cc);                                                 \
        if (_tb != 0) STEP(_tb, P0);  /* skips only t=0 (chunk 0) */              \
        STEP(_tb + 1, P1);                                                        \
        STEP(_tb + 2, P2);                                                        \
        STEP(_tb + 3, P3);                                                        \
        P0 = _n0; P1 = _n1; P2 = _n2; P3 = _n3;                                   \
    }

    // prologue: 16 chunks (rows 0..63) in flight
#pragma unroll
    for (int c0 = 0; c0 < 16; ++c0) GLLC(c0);
    // younger(GLL0)=15, younger(GLL1)=14 -> vmcnt(14) covers both
    asm volatile("s_waitcnt vmcnt(14)" ::: "memory");
    float pa0 = ring[0 * 256 + 0 * 64 + lane];
    float pa1 = ring[0 * 256 + 1 * 64 + lane];
    float pa2 = ring[0 * 256 + 2 * 64 + lane];
    float pa3 = ring[0 * 256 + 3 * 64 + lane];
    float pb0 = ring[1 * 256 + 0 * 64 + lane];
    float pb1 = ring[1 * 256 + 1 * 64 + lane];
    float pb2 = ring[1 * 256 + 2 * 64 + lane];
    float pb3 = ring[1 * 256 + 3 * 64 + lane];

    // warm-up iterations: store count still low -> conservative vmcnt(14)
    for (int cc = 0; cc < 14; cc += 2) {
        HALF(cc,     "s_waitcnt vmcnt(14)", pa0, pa1, pa2, pa3);
        HALF(cc + 1, "s_waitcnt vmcnt(14)", pb0, pb1, pb2, pb3);
    }
    // steady state: younger(GLL(cc+2)) = 14 + 4*cc >= 70 -> vmcnt(63) safe, never drains
    for (int cc = 14; cc < 500; cc += 2) {
        HALF(cc,     "s_waitcnt vmcnt(63)", pa0, pa1, pa2, pa3);
        HALF(cc + 1, "s_waitcnt vmcnt(63)", pb0, pb1, pb2, pb3);
    }
    // chunks 0..499 computed -> t = 1..1999 all done

#undef HALF
#undef STEP
#undef GLLC
}

extern "C" void kernel_launch(void* const* d_in, const int* in_sizes, int n_in,
                              void* d_out, int out_size, void* d_ws, size_t ws_size,
                              hipStream_t stream) {
    const float* x       = (const float*)d_in[0];
    const float* w       = (const float*)d_in[1];
    const float* v_th    = (const float*)d_in[2];
    const float* v_rest  = (const float*)d_in[3];
    const float* v_reset = (const float*)d_in[4];
    const float* t_ref   = (const float*)d_in[5];
    const float* tau     = (const float*)d_in[6];
    float* out = (float*)d_out;

    const size_t LIF_B = (size_t)MPAD * NOUT_N * 4;        //  32 MiB
    const size_t XS_B  = (size_t)MPAD * NIN_K * 2;         //  32 MiB each
    const size_t WS_B  = (size_t)NOUT_N * NIN_K * 2;       //  64 MiB each
    const size_t NEED  = LIF_B + 2 * XS_B + 2 * WS_B;      // 224 MiB

    char* ws = (char*)d_ws;
    float* lif = (float*)ws;

    if (ws_size >= NEED) {
        _Float16* x0 = (_Float16*)(ws + LIF_B);
        _Float16* x1 = (_Float16*)(ws + LIF_B + XS_B);
        _Float16* w0 = (_Float16*)(ws + LIF_B + 2 * XS_B);
        _Float16* w1 = (_Float16*)(ws + LIF_B + 2 * XS_B + WS_B);

        const size_t nx = (size_t)MPAD * NIN_K;
        split_f32<<<nx / 8 / 256, 256, 0, stream>>>(x, x0, x1,
                                                    (size_t)T_STEPS * NIN_K);
        const size_t nw = (size_t)NOUT_N * NIN_K;
        split_f32<<<nw / 8 / 256, 256, 0, stream>>>(w, w0, w1, nw);

        dim3 g(NOUT_N / 128, MPAD / 128);
        gemm_f16x2<<<g, 256, 0, stream>>>(x0, x1, w0, w1, lif);
    } else {
        dim3 g(NOUT_N / BN, (T_STEPS + BM - 1) / BM);
        gemm_bt<<<g, 256, 0, stream>>>(x, w, lif, T_STEPS, NOUT_N, NIN_K);
        const size_t padn = (size_t)(MPAD - T_STEPS) * NOUT_N;
        zero_rows<<<(padn + 255) / 256, 256, 0, stream>>>(lif + (size_t)T_STEPS * NOUT_N, padn);
    }

    lif_scan<<<NOUT_N / 64, 64, 0, stream>>>(lif, v_th, v_rest, v_reset, t_ref, tau, out);
}

// Round 2
// 693.588 us; speedup vs baseline: 1.0409x; 1.0407x over previous
//
#include <hip/hip_runtime.h>
#include <hip/hip_bf16.h>

// LIF layer: lif_input[T,NOUT] = x[T,NIN] @ W[NOUT,NIN]^T (fp32), then sequential scan.
// fp32 GEMM on matrix pipe via fp16 2-way SCALED split, 3 MFMA products:
//   a = a0 + a1*2^-12 (a1 pre-scaled by 2^12: dodges fp16 subnormal flush)
//   C = acc0(A0B0) + 2^-12 * acc1(A0B1 + A1B0); error ~2^-24|ab| (fp32-noise level).
// Round-8 change (scan only; GEMM untouched for attribution):
//  - Round 7 (LDS ring + global_load_lds + counted vmcnt) was a perfect null
//    (722 -> 722 us). Suspect: compiler waitcnt pass conservatively draining
//    around global_load_lds -> ds_read (invisible to source asm), leaving one
//    full HBM latency per 4-row chunk (~1250 cy/chunk == the missing ~260 us).
//  - Round 8: scan uses ONLY inline-asm VMEM (global_load_dword into 32 NAMED
//    loop-carried registers, global_store_dword for spikes). Inline-asm memory
//    ops are opaque to the compiler's waitcnt insertion (it cannot serialize
//    them) and volatile asms are never reordered among themselves (younger-op
//    counting is exact). Per-step "s_waitcnt vmcnt(62)" ("+v"-tied to the
//    consumed register; 31 for the first group) guarantees the row-t load
//    retired via in-order retirement: exactly 62 (31+d) younger VMEM ops.
//    Equilibrium outstanding ~56 < 62 -> steady state never stalls.
//  - 61 steady groups as a RUNTIME loop (#pragma unroll 1): body ~5 KB, L1I-
//    resident (round-6's 2000-step straight-line code streamed ~250 KB of
//    instructions -- a plausible I-fetch bound).
//  - If this round is ALSO null, the scan is exonerated (this version has a
//    provable ~30 us floor) and the missing time is splits/launch structure.

#define T_STEPS 2000
#define NIN_K   8192
#define NOUT_N  4096
#define MPAD    2048

typedef __attribute__((ext_vector_type(8))) _Float16 half8;  // 8 fp16 = 4 VGPRs
typedef __attribute__((ext_vector_type(4))) float f32x4;

#define GLL16(g, l)                                                              \
    __builtin_amdgcn_global_load_lds(                                            \
        (const __attribute__((address_space(1))) void*)(g),                      \
        (__attribute__((address_space(3))) void*)(l), 16, 0, 0)

// ---------------- decompose: fp32 -> (hi, lo*2^12) fp16 ----------------
__global__ __launch_bounds__(256) void split_f32(const float* __restrict__ src,
                                                 _Float16* __restrict__ hi,
                                                 _Float16* __restrict__ lo,
                                                 size_t n_valid) {
    const size_t i8 = (size_t)(blockIdx.x * 256u + threadIdx.x) * 8;
    float vv[8];
    if (i8 < n_valid) {
        float4 v0 = *(const float4*)(src + i8);
        float4 v1 = *(const float4*)(src + i8 + 4);
        vv[0] = v0.x; vv[1] = v0.y; vv[2] = v0.z; vv[3] = v0.w;
        vv[4] = v1.x; vv[5] = v1.y; vv[6] = v1.z; vv[7] = v1.w;
    } else {
#pragma unroll
        for (int j = 0; j < 8; ++j) vv[j] = 0.f;
    }
    half8 h8, l8;
#pragma unroll
    for (int j = 0; j < 8; ++j) {
        _Float16 h = (_Float16)vv[j];               // RN
        float r = __fsub_rn(vv[j], (float)h);       // exact
        h8[j] = h;
        l8[j] = (_Float16)(r * 4096.0f);            // exact shift + one RN
    }
    *(half8*)(hi + i8) = h8;
    *(half8*)(lo + i8) = l8;
}

// ---------------- split-fp16 MFMA GEMM, BK=64 ----------------
// Block tile 128x128, 4 waves of 64x64 (4x4 frags of 16x16x32), 128 K-iters.
// LDS row layout: [row][64 halves] = 128 B/row; 16B slot s of row r holds TRUE
// k-group s^(r&7) (stage-side per-lane global-address swizzle). Fragment for
// (kstep,quad) reads slot (kstep*4+quad)^(r&7) -> 8 distinct banks, 2-way, free.
// NOTE: per K=32 substep each wave reads 16 KB LDS for 48 MFMAs = 341 B/MFMA;
// at full MFMA rate ~410 B/cyc/CU vs 256 B/clk LDS port -> MfmaUtil capped
// ~62%. Measured 52%, bank-conflict=0: near the LDS-BW structural cap.
__global__ __launch_bounds__(256, 2) void gemm_f16x2(const _Float16* __restrict__ A0,
                                                     const _Float16* __restrict__ A1,
                                                     const _Float16* __restrict__ B0,
                                                     const _Float16* __restrict__ B1,
                                                     float* __restrict__ C) {
    __shared__ _Float16 lds[4][128 * 64];  // A0,A1,B0,B1: 16 KB each = 64 KB

    const int tid  = threadIdx.x;
    const int wave = tid >> 6;
    const int lane = tid & 63;
    const int bm = blockIdx.y * 128;
    const int bn = blockIdx.x * 128;
    const int wm = (wave >> 1) * 64;
    const int wn = (wave & 1) * 64;

    // Staging: per c-chunk, thread covers row c*32 + (tid>>3), 16B slot tid&7.
    // Global k-group swizzled: (tid&7) ^ ((tid>>3)&7)  [(tid>>3)&7 == row&7]
    const int srow = tid >> 3;                       // 0..31
    const int skswz = ((tid & 7) ^ (srow & 7)) * 8;  // halves

    f32x4 acc0[4][4], acc1[4][4];
#pragma unroll
    for (int i = 0; i < 4; ++i)
#pragma unroll
        for (int j = 0; j < 4; ++j) {
            acc0[i][j] = (f32x4){0.f, 0.f, 0.f, 0.f};
            acc1[i][j] = (f32x4){0.f, 0.f, 0.f, 0.f};
        }

    const int quad = lane >> 4;
    const int l16  = lane & 15;

    for (int k0 = 0; k0 < NIN_K; k0 += 64) {
        __syncthreads();  // previous compute done before overwriting LDS
#pragma unroll
        for (int c = 0; c < 4; ++c) {  // 4 chunks of 32 rows
            const size_t ga = (size_t)(bm + c * 32 + srow) * NIN_K + k0 + skswz;
            const size_t gb = (size_t)(bn + c * 32 + srow) * NIN_K + k0 + skswz;
            const int base = (c * 32 + wave * 8) * 64;  // wave-uniform (HW adds lane*16B)
            GLL16(A0 + ga, &lds[0][base]);
            GLL16(A1 + ga, &lds[1][base]);
            GLL16(B0 + gb, &lds[2][base]);
            GLL16(B1 + gb, &lds[3][base]);
        }
        __syncthreads();  // staging complete

#pragma unroll
        for (int ks = 0; ks < 2; ++ks) {  // two K=32 sub-steps
            half8 b0f[4], b1f[4];
#pragma unroll
            for (int j = 0; j < 4; ++j) {
                const int row = wn + j * 16 + l16;
                const int off = row * 64 + ((ks * 4 + quad) ^ (row & 7)) * 8;
                b0f[j] = *(const half8*)&lds[2][off];
                b1f[j] = *(const half8*)&lds[3][off];
            }
#pragma unroll
            for (int i = 0; i < 4; ++i) {
                const int row = wm + i * 16 + l16;
                const int off = row * 64 + ((ks * 4 + quad) ^ (row & 7)) * 8;
                const half8 a0f = *(const half8*)&lds[0][off];
                const half8 a1f = *(const half8*)&lds[1][off];
#pragma unroll
                for (int j = 0; j < 4; ++j) {
                    acc0[i][j] = __builtin_amdgcn_mfma_f32_16x16x32_f16(a0f, b0f[j], acc0[i][j], 0, 0, 0);
                    acc1[i][j] = __builtin_amdgcn_mfma_f32_16x16x32_f16(a0f, b1f[j], acc1[i][j], 0, 0, 0);
                    acc1[i][j] = __builtin_amdgcn_mfma_f32_16x16x32_f16(a1f, b0f[j], acc1[i][j], 0, 0, 0);
                }
            }
        }
    }

    // C/D layout (m89-verified): col = lane&15, row = quad*4 + reg
    const float s = 1.0f / 4096.0f;
#pragma unroll
    for (int i = 0; i < 4; ++i)
#pragma unroll
        for (int j = 0; j < 4; ++j) {
            const int m = bm + wm + i * 16 + quad * 4;
            const int n = bn + wn + j * 16 + l16;
            float* cp = C + (size_t)m * NOUT_N + n;
#pragma unroll
            for (int r = 0; r < 4; ++r)
                cp[(size_t)r * NOUT_N] = __fmaf_rn(acc1[i][j][r], s, acc0[i][j][r]);
        }
}

// ---------------- fallback fp32 GEMM (round-1 proven; reads RAW x/w) ----------------
#define BM 64
#define BN 64
#define BK 16
#define PAD 4
__global__ __launch_bounds__(256) void gemm_bt(const float* __restrict__ A,
                                               const float* __restrict__ B,
                                               float* __restrict__ C,
                                               int M, int N, int K) {
    __shared__ float As[BK][BM + PAD];
    __shared__ float Bs[BK][BN + PAD];
    const int bm = blockIdx.y * BM, bn = blockIdx.x * BN;
    const int tid = threadIdx.x;
    const int tx = tid & 15, ty = tid >> 4;
    const int lrow = tid >> 2, lk = (tid & 3) * 4;
    float acc[4][4];
#pragma unroll
    for (int i = 0; i < 4; ++i)
#pragma unroll
        for (int j = 0; j < 4; ++j) acc[i][j] = 0.0f;
    for (int k0 = 0; k0 < K; k0 += BK) {
        const int am = bm + lrow;
        float4 av = (am < M) ? *(const float4*)(A + (size_t)am * K + k0 + lk)
                             : make_float4(0.f, 0.f, 0.f, 0.f);
        As[lk + 0][lrow] = av.x; As[lk + 1][lrow] = av.y;
        As[lk + 2][lrow] = av.z; As[lk + 3][lrow] = av.w;
        float4 bv = *(const float4*)(B + (size_t)(bn + lrow) * K + k0 + lk);
        Bs[lk + 0][lrow] = bv.x; Bs[lk + 1][lrow] = bv.y;
        Bs[lk + 2][lrow] = bv.z; Bs[lk + 3][lrow] = bv.w;
        __syncthreads();
#pragma unroll
        for (int k = 0; k < BK; ++k) {
            float a[4], b[4];
#pragma unroll
            for (int i = 0; i < 4; ++i) a[i] = As[k][ty * 4 + i];
#pragma unroll
            for (int j = 0; j < 4; ++j) b[j] = Bs[k][tx * 4 + j];
#pragma unroll
            for (int i = 0; i < 4; ++i)
#pragma unroll
                for (int j = 0; j < 4; ++j) acc[i][j] += a[i] * b[j];
        }
        __syncthreads();
    }
#pragma unroll
    for (int i = 0; i < 4; ++i) {
        const int m = bm + ty * 4 + i;
        if (m < M) {
            float* cp = C + (size_t)m * N + bn + tx * 4;
#pragma unroll
            for (int j = 0; j < 4; ++j) cp[j] = acc[i][j];
        }
    }
}

// zero-fill pad rows of lif (fallback path only; main path writes them via GEMM)
__global__ void zero_rows(float* __restrict__ p, size_t n) {
    const size_t i = (size_t)blockIdx.x * 256 + threadIdx.x;
    if (i < n) p[i] = 0.0f;
}

// ---------------- sequential LIF scan (round 8: all-asm register ring) ----------------
// One wave per 64 neurons. Depth-32 register ring p00..p31 (one lif row each).
// ALL VMEM in the hot loop is volatile inline asm:
//   - loads:  global_load_dword  -> named register (compiler waitcnt pass can't
//             see them -> cannot insert serializing drains; named scalars can't
//             be scratch-demoted)
//   - stores: global_store_dword (volatile asms stay in program order -> exact
//             younger-op accounting for the counted vmcnt)
// Per-step order: [waitcnt tied to PD via "+v"] [compute+store row t] [load row
// t+32 into PD]. Younger-op count for the row-t load at its waitcnt:
//   steady groups: 31 steps x (store+load) = 62  -> vmcnt(62)
//   first group:   (31-d) prologue loads + 2d    -> >=31 -> vmcnt(31)
// In-order vmcnt retirement (m135) => load retired when wait passes. Steady
// outstanding ~2*900cy/32cy ~ 56 < 62 => no stall; serial-VALU floor ~27 us.
// Loads cover rows 1..2016 (<=2047; rows >=2000 are zero-padded by the GEMM).
__global__ __launch_bounds__(64) void lif_scan(const float* __restrict__ inp,
                                               const float* __restrict__ v_th_p,
                                               const float* __restrict__ v_rest_p,
                                               const float* __restrict__ v_reset_p,
                                               const float* __restrict__ t_ref_p,
                                               const float* __restrict__ tau_p,
                                               float* __restrict__ out) {
    const int lane = threadIdx.x;  // 0..63, one wave
    const int j = blockIdx.x * 64 + lane;

    const float vth = v_th_p[j], vrest = v_rest_p[j], vres = v_reset_p[j];
    const float tref = t_ref_p[j];
    const float cleak = __fmul_rn(0.001f, tau_p[j]);
    float v = vrest, refrac = 0.0f;
    out[j] = 0.0f;  // row 0 stays zero

    const float* plv = inp + (size_t)1 * NOUT_N + j;  // next row to LOAD (starts at row 1)
    float* pst = out + (size_t)1 * NOUT_N + j;        // next row to STORE (starts at t=1)

    float p00, p01, p02, p03, p04, p05, p06, p07, p08, p09, p10, p11, p12, p13, p14, p15;
    float p16, p17, p18, p19, p20, p21, p22, p23, p24, p25, p26, p27, p28, p29, p30, p31;

#define LDP(PD)                                                                   \
    asm volatile("global_load_dword %0, %1, off" : "=v"(PD) : "v"(plv) : "memory"); \
    plv += NOUT_N;

// one LIF step: wait for PD's load, consume it, store spike, prefetch row t+32
// into PD. Arithmetic bit-identical to previous rounds.
#define STEPA(PD, WSTR)                                                           \
    {                                                                             \
        asm volatile(WSTR : "+v"(PD)::"memory");                                  \
        const float in = PD;                                                      \
        const float dd = __fmul_rn(cleak, __fsub_rn(v, vrest));                   \
        v = __fsub_rn(v, dd);                                                     \
        v = (refrac == 0.0f) ? __fadd_rn(v, in) : v;                              \
        refrac = (refrac > 0.0f) ? (refrac - 0.001f) : 0.0f;                      \
        const bool s = (__fsub_rn(v, vth) >= 0.0f);                               \
        const float spk = s ? 1.0f : 0.0f;                                        \
        asm volatile("global_store_dword %0, %1, off" ::"v"(pst), "v"(spk)        \
                     : "memory");                                                 \
        pst += NOUT_N;                                                            \
        asm volatile("global_load_dword %0, %1, off" : "=v"(PD) : "v"(plv)        \
                     : "memory");                                                 \
        plv += NOUT_N;                                                            \
        refrac = s ? tref : refrac;                                               \
        v = s ? vres : v;                                                         \
    }

#define GROUP32(WSTR)                                                             \
    STEPA(p00, WSTR) STEPA(p01, WSTR) STEPA(p02, WSTR) STEPA(p03, WSTR)           \
    STEPA(p04, WSTR) STEPA(p05, WSTR) STEPA(p06, WSTR) STEPA(p07, WSTR)           \
    STEPA(p08, WSTR) STEPA(p09, WSTR) STEPA(p10, WSTR) STEPA(p11, WSTR)           \
    STEPA(p12, WSTR) STEPA(p13, WSTR) STEPA(p14, WSTR) STEPA(p15, WSTR)           \
    STEPA(p16, WSTR) STEPA(p17, WSTR) STEPA(p18, WSTR) STEPA(p19, WSTR)           \
    STEPA(p20, WSTR) STEPA(p21, WSTR) STEPA(p22, WSTR) STEPA(p23, WSTR)           \
    STEPA(p24, WSTR) STEPA(p25, WSTR) STEPA(p26, WSTR) STEPA(p27, WSTR)           \
    STEPA(p28, WSTR) STEPA(p29, WSTR) STEPA(p30, WSTR) STEPA(p31, WSTR)

// tail step (loads already waited; plain store, compiler handles end-of-kernel)
#define TAILSTEP(PD)                                                              \
    {                                                                             \
        const float in = PD;                                                      \
        const float dd = __fmul_rn(cleak, __fsub_rn(v, vrest));                   \
        v = __fsub_rn(v, dd);                                                     \
        v = (refrac == 0.0f) ? __fadd_rn(v, in) : v;                              \
        refrac = (refrac > 0.0f) ? (refrac - 0.001f) : 0.0f;                      \
        const bool s = (__fsub_rn(v, vth) >= 0.0f);                               \
        *pst = s ? 1.0f : 0.0f;                                                   \
        pst += NOUT_N;                                                            \
        refrac = s ? tref : refrac;                                               \
        v = s ? vres : v;                                                         \
    }

    // prologue: rows 1..32 in flight
    LDP(p00) LDP(p01) LDP(p02) LDP(p03) LDP(p04) LDP(p05) LDP(p06) LDP(p07)
    LDP(p08) LDP(p09) LDP(p10) LDP(p11) LDP(p12) LDP(p13) LDP(p14) LDP(p15)
    LDP(p16) LDP(p17) LDP(p18) LDP(p19) LDP(p20) LDP(p21) LDP(p22) LDP(p23)
    LDP(p24) LDP(p25) LDP(p26) LDP(p27) LDP(p28) LDP(p29) LDP(p30) LDP(p31)

    // group 0: t = 1..32 (prefetch rows 33..64); younger(load row 1+d) = 31+d
    GROUP32("s_waitcnt vmcnt(31)")

    // steady: 61 groups, t = 33..1984 (prefetch up to row 2016); younger = 62
#pragma unroll 1
    for (int g = 1; g < 62; ++g) {
        GROUP32("s_waitcnt vmcnt(62)")
    }

    // drain everything (also flushes all asm stores before endpgm)
    asm volatile("s_waitcnt vmcnt(0)" ::: "memory");
    __builtin_amdgcn_sched_barrier(0);  // rule #18: no reg-use hoisting above the wait

    // tail: t = 1985..1999 from p00..p14 (loaded as rows 1985..1999)
    TAILSTEP(p00) TAILSTEP(p01) TAILSTEP(p02) TAILSTEP(p03) TAILSTEP(p04)
    TAILSTEP(p05) TAILSTEP(p06) TAILSTEP(p07) TAILSTEP(p08) TAILSTEP(p09)
    TAILSTEP(p10) TAILSTEP(p11) TAILSTEP(p12) TAILSTEP(p13) TAILSTEP(p14)

#undef LDP
#undef STEPA
#undef GROUP32
#undef TAILSTEP
}

extern "C" void kernel_launch(void* const* d_in, const int* in_sizes, int n_in,
                              void* d_out, int out_size, void* d_ws, size_t ws_size,
                              hipStream_t stream) {
    const float* x       = (const float*)d_in[0];
    const float* w       = (const float*)d_in[1];
    const float* v_th    = (const float*)d_in[2];
    const float* v_rest  = (const float*)d_in[3];
    const float* v_reset = (const float*)d_in[4];
    const float* t_ref   = (const float*)d_in[5];
    const float* tau     = (const float*)d_in[6];
    float* out = (float*)d_out;

    const size_t LIF_B = (size_t)MPAD * NOUT_N * 4;        //  32 MiB
    const size_t XS_B  = (size_t)MPAD * NIN_K * 2;         //  32 MiB each
    const size_t WS_B  = (size_t)NOUT_N * NIN_K * 2;       //  64 MiB each
    const size_t NEED  = LIF_B + 2 * XS_B + 2 * WS_B;      // 224 MiB

    char* ws = (char*)d_ws;
    float* lif = (float*)ws;

    if (ws_size >= NEED) {
        _Float16* x0 = (_Float16*)(ws + LIF_B);
        _Float16* x1 = (_Float16*)(ws + LIF_B + XS_B);
        _Float16* w0 = (_Float16*)(ws + LIF_B + 2 * XS_B);
        _Float16* w1 = (_Float16*)(ws + LIF_B + 2 * XS_B + WS_B);

        const size_t nx = (size_t)MPAD * NIN_K;
        split_f32<<<nx / 8 / 256, 256, 0, stream>>>(x, x0, x1,
                                                    (size_t)T_STEPS * NIN_K);
        const size_t nw = (size_t)NOUT_N * NIN_K;
        split_f32<<<nw / 8 / 256, 256, 0, stream>>>(w, w0, w1, nw);

        dim3 g(NOUT_N / 128, MPAD / 128);
        gemm_f16x2<<<g, 256, 0, stream>>>(x0, x1, w0, w1, lif);
    } else {
        dim3 g(NOUT_N / BN, (T_STEPS + BM - 1) / BM);
        gemm_bt<<<g, 256, 0, stream>>>(x, w, lif, T_STEPS, NOUT_N, NIN_K);
        const size_t padn = (size_t)(MPAD - T_STEPS) * NOUT_N;
        zero_rows<<<(padn + 255) / 256, 256, 0, stream>>>(lif + (size_t)T_STEPS * NOUT_N, padn);
    }

    lif_scan<<<NOUT_N / 64, 64, 0, stream>>>(lif, v_th, v_rest, v_reset, t_ref, tau, out);
}